// Round 8
// baseline (250.346 us; speedup 1.0000x reference)
//
#include <hip/hip_runtime.h>

#define CH 224
#define NF 14           // n-fragments = 224/16
#define EPS 5e-4f       // approx-score gap below which we re-resolve exactly

typedef __attribute__((ext_vector_type(8))) short bf16x8;
typedef __attribute__((ext_vector_type(4))) float f32x4;

__device__ inline unsigned short f2bf(float x) {
    unsigned int u = __builtin_bit_cast(unsigned int, x);
    return (unsigned short)((u + 0x7FFFu + ((u >> 16) & 1u)) >> 16);   // RNE
}
__device__ inline float bf2f(unsigned short h) {
    unsigned int u = ((unsigned int)h) << 16;
    return __builtin_bit_cast(float, u);
}

// ---------------------------------------------------------------------------
// Prep: w (fp32) -> wt: MFMA-fragment-ordered bf16 hi/lo tiles + wsqh.
// Layout (shorts): wt[ch*14336 + nf*1024 + hl*512 + l*8 + pos] where for
// element w[k][c]: ch=c/32, nf=k/16, l=(k&15)|(((c&31)>>3)<<4), pos=c&7.
// Lane l reads its B-fragment as 16B at (ch,nf,hl) tile + l*16.
// wsqh reduction order identical to round-1's proven-matching kernel.
// ---------------------------------------------------------------------------
__global__ void wprep_kernel(const float* __restrict__ w,
                             short* __restrict__ wt,
                             float* __restrict__ wsqh) {
    const int k = blockIdx.x, lane = threadIdx.x;    // 224 blocks x 64
    float s = 0.f;
    for (int c = lane; c < CH; c += 64) {
        const float v = w[k * CH + c];
        const unsigned short h = f2bf(v);
        const unsigned short lo = f2bf(v - bf2f(h));
        const int base = (c >> 5) * 14336 + (k >> 4) * 1024
                       + (((k & 15) | (((c & 31) >> 3) << 4)) * 8) + (c & 7);
        wt[base]       = (short)h;     // hl = 0
        wt[base + 512] = (short)lo;    // hl = 1
        s = fmaf(v, v, s);
    }
    for (int off = 32; off > 0; off >>= 1) s += __shfl_down(s, off);
    if (lane == 0) wsqh[k] = 0.5f * s;
}

// ---------------------------------------------------------------------------
// Main: 1 wave per block, 32 rows x 224 codes, processed as two k-halves of
// 112 codes with a (v1,v2,k1) top-2 register carry between halves (halves the
// accumulator file -> 4 waves/SIMD). No LDS staging, no main-loop barriers:
// X fragments global->reg, W fragments global->reg from L2-resident wt image.
// MFMA values & order bit-identical to the round-4/6-proven kernel.
// ---------------------------------------------------------------------------
__global__ __launch_bounds__(64, 4) void som_mfma(
    const float* __restrict__ inp, const float* __restrict__ w,
    const short* __restrict__ wt, const float* __restrict__ wsqh,
    float* __restrict__ out)
{
    __shared__ int bmu_sh[32];
    __shared__ unsigned char flg_sh[32];

    const int lane = threadIdx.x;
    const int mw   = blockIdx.x * 32;        // 32-aligned -> single b per wave
    const int bb   = mw / CH;
    const int t0   = mw % CH;
    const int col  = lane & 15;
    const int g    = lane >> 4;

    const float* xbase = inp + (size_t)bb * CH * CH + t0 + col;

    // top-2 carry per (mf, r)
    float cv1[2][4], cv2[2][4];
    int   ck1[2][4];
    #pragma unroll
    for (int mf = 0; mf < 2; ++mf)
        #pragma unroll
        for (int r = 0; r < 4; ++r) {
            cv1[mf][r] = -1e30f; cv2[mf][r] = -1e30f; ck1[mf][r] = 0;
        }

    #pragma unroll 1
    for (int kh = 0; kh < 2; ++kh) {
        f32x4 acc[2][7];
        #pragma unroll
        for (int mf = 0; mf < 2; ++mf)
            #pragma unroll
            for (int nf = 0; nf < 7; ++nf)
                acc[mf][nf] = (f32x4){0.f, 0.f, 0.f, 0.f};

        #pragma unroll 1
        for (int ch = 0; ch < 7; ++ch) {
            const int cb = ch * 32;

            // ---- X fragment loads (global -> regs) ----
            float xv[2][8];
            #pragma unroll
            for (int mf = 0; mf < 2; ++mf)
                #pragma unroll
                for (int j = 0; j < 8; ++j)
                    xv[mf][j] = xbase[(size_t)(cb + g * 8 + j) * CH + mf * 16];

            // ---- convert X to hi/lo bf16 fragments ----
            bf16x8 afh[2], afl[2];
            #pragma unroll
            for (int mf = 0; mf < 2; ++mf)
                #pragma unroll
                for (int j = 0; j < 8; ++j) {
                    const unsigned short h = f2bf(xv[mf][j]);
                    afh[mf][j] = (short)h;
                    afl[mf][j] = (short)f2bf(xv[mf][j] - bf2f(h));
                }

            // ---- W fragments straight from L2; MFMA ----
            const short* wbase = wt + ch * 14336 + kh * 7 * 1024 + lane * 8;
            #pragma unroll
            for (int nf7 = 0; nf7 < 7; ++nf7) {
                const bf16x8 bh = *(const bf16x8*)(wbase + nf7 * 1024);
                const bf16x8 bl = *(const bf16x8*)(wbase + nf7 * 1024 + 512);
                #pragma unroll
                for (int mf = 0; mf < 2; ++mf) {
                    acc[mf][nf7] = __builtin_amdgcn_mfma_f32_16x16x32_bf16(afh[mf], bh, acc[mf][nf7], 0, 0, 0);
                    acc[mf][nf7] = __builtin_amdgcn_mfma_f32_16x16x32_bf16(afh[mf], bl, acc[mf][nf7], 0, 0, 0);
                    acc[mf][nf7] = __builtin_amdgcn_mfma_f32_16x16x32_bf16(afl[mf], bh, acc[mf][nf7], 0, 0, 0);
                }
            }
        }

        // ---- fold this half into the top-2 carry (same scan order as before) ----
        float wq[7];
        #pragma unroll
        for (int nf7 = 0; nf7 < 7; ++nf7)
            wq[nf7] = wsqh[(kh * 7 + nf7) * 16 + col];

        #pragma unroll
        for (int mf = 0; mf < 2; ++mf)
            #pragma unroll
            for (int r = 0; r < 4; ++r) {
                float v1 = cv1[mf][r], v2 = cv2[mf][r];
                int   k1 = ck1[mf][r];
                #pragma unroll
                for (int nf7 = 0; nf7 < 7; ++nf7) {
                    const float s = acc[mf][nf7][r] - wq[nf7];
                    const int k = (kh * 7 + nf7) * 16 + col;
                    if (s > v1 || (s == v1 && k < k1)) { v2 = v1; v1 = s; k1 = k; }
                    else if (s > v2) v2 = s;
                }
                cv1[mf][r] = v1; cv2[mf][r] = v2; ck1[mf][r] = k1;
            }
    }

    // ---- 16-lane lexicographic reduce (identical to proven kernel) ----
    #pragma unroll
    for (int mf = 0; mf < 2; ++mf)
        #pragma unroll
        for (int r = 0; r < 4; ++r) {
            float v1 = cv1[mf][r], v2 = cv2[mf][r];
            int   k1 = ck1[mf][r];
            #pragma unroll
            for (int mm = 1; mm < 16; mm <<= 1) {
                const float ov1 = __shfl_xor(v1, mm);
                const int   ok1 = __shfl_xor(k1, mm);
                const float ov2 = __shfl_xor(v2, mm);
                if (ov1 > v1 || (ov1 == v1 && ok1 < k1)) { v2 = fmaxf(v1, ov2); v1 = ov1; k1 = ok1; }
                else                                     { v2 = fmaxf(v2, ov1); }
            }
            if (col == 0) {
                const int trow = mf * 16 + g * 4 + r;
                bmu_sh[trow] = k1;
                flg_sh[trow] = (v1 - v2 < EPS) ? 1 : 0;
            }
        }

    __syncthreads();

    // ---- exact re-resolve of flagged rows (rare; replicates round-1 math) ----
    for (int tl = 0; tl < 32; ++tl) {
        if (!flg_sh[tl]) continue;
        const int tg = t0 + tl;
        const float* xp = inp + (size_t)bb * CH * CH + tg;
        float s0 = 0.f, s1 = 0.f, s2 = 0.f, s3 = 0.f;
        const int k0 = lane, k1a = lane + 64, k2 = lane + 128, k3 = lane + 192;
        for (int c = 0; c < CH; c += 4) {
            float xc[4];
            #pragma unroll
            for (int i = 0; i < 4; ++i) xc[i] = xp[(size_t)(c + i) * CH];
            const float4 w0 = *(const float4*)(w + (size_t)k0  * CH + c);
            const float4 w1 = *(const float4*)(w + (size_t)k1a * CH + c);
            const float4 w2 = *(const float4*)(w + (size_t)k2  * CH + c);
            s0 = fmaf(xc[0], w0.x, s0); s0 = fmaf(xc[1], w0.y, s0); s0 = fmaf(xc[2], w0.z, s0); s0 = fmaf(xc[3], w0.w, s0);
            s1 = fmaf(xc[0], w1.x, s1); s1 = fmaf(xc[1], w1.y, s1); s1 = fmaf(xc[2], w1.z, s1); s1 = fmaf(xc[3], w1.w, s1);
            s2 = fmaf(xc[0], w2.x, s2); s2 = fmaf(xc[1], w2.y, s2); s2 = fmaf(xc[2], w2.z, s2); s2 = fmaf(xc[3], w2.w, s2);
            if (k3 < CH) {
                const float4 w3 = *(const float4*)(w + (size_t)k3 * CH + c);
                s3 = fmaf(xc[0], w3.x, s3); s3 = fmaf(xc[1], w3.y, s3); s3 = fmaf(xc[2], w3.z, s3); s3 = fmaf(xc[3], w3.w, s3);
            }
        }
        float bs = -1e30f; int bk = 1 << 30;
        {
            const float c0v = s0 - wsqh[k0];
            if (c0v > bs || (c0v == bs && k0 < bk)) { bs = c0v; bk = k0; }
            const float c1v = s1 - wsqh[k1a];
            if (c1v > bs || (c1v == bs && k1a < bk)) { bs = c1v; bk = k1a; }
            const float c2v = s2 - wsqh[k2];
            if (c2v > bs || (c2v == bs && k2 < bk)) { bs = c2v; bk = k2; }
            if (k3 < CH) {
                const float c3v = s3 - wsqh[k3];
                if (c3v > bs || (c3v == bs && k3 < bk)) { bs = c3v; bk = k3; }
            }
        }
        for (int mm = 1; mm < 64; mm <<= 1) {
            const float ob = __shfl_xor(bs, mm);
            const int   ok = __shfl_xor(bk, mm);
            if (ob > bs || (ob == bs && ok < bk)) { bs = ob; bk = ok; }
        }
        if (lane == 0) bmu_sh[tl] = bk;
    }

    __syncthreads();

    // ---- one-hot write: out[b, k, t0..t0+31] ----
    #pragma unroll
    for (int j = 0; j < 28; ++j) {
        const int f  = lane + 64 * j;       // 0..1791
        const int k  = f >> 3;              // 0..223
        const int t4 = (f & 7) * 4;
        float4 v;
        v.x = (bmu_sh[t4 + 0] == k) ? 1.f : 0.f;
        v.y = (bmu_sh[t4 + 1] == k) ? 1.f : 0.f;
        v.z = (bmu_sh[t4 + 2] == k) ? 1.f : 0.f;
        v.w = (bmu_sh[t4 + 3] == k) ? 1.f : 0.f;
        *(float4*)(out + (size_t)bb * CH * CH + (size_t)k * CH + t0 + t4) = v;
    }
}

extern "C" void kernel_launch(void* const* d_in, const int* in_sizes, int n_in,
                              void* d_out, int out_size, void* d_ws, size_t ws_size,
                              hipStream_t stream) {
    const float* inp = (const float*)d_in[0];   // (512, 224, 224) fp32
    const float* w   = (const float*)d_in[1];   // (224, 224) fp32
    float* out = (float*)d_out;

    short* wt   = (short*)d_ws;                 // 7*14*2*64*8 = 100352 shorts
    float* wsqh = (float*)(wt + 7 * 14 * 2 * 64 * 8);   // 224 fp32

    const int batch = in_sizes[0] / (CH * CH);  // 512
    const int mtot  = batch * CH;               // 114688

    wprep_kernel<<<CH, 64, 0, stream>>>(w, wt, wsqh);
    som_mfma<<<mtot / 32, 64, 0, stream>>>(inp, w, wt, wsqh, out);
}